// Round 1
// baseline (162.265 us; speedup 1.0000x reference)
//
#include <hip/hip_runtime.h>
#include <hip/hip_bf16.h>

#define NLIG 1024
#define NREC 4096
#define NTOT 5120
#define ELIG 8192
#define ETOT 40960
#define TSTRIDE 1088   // 17 slots * 64

struct Params {
  const float *lig_x, *rec_x, *lig_e, *rec_e;
  const int *lig_src, *lig_dst, *rec_src, *rec_dst;
  const float *nW[2], *nb[2], *eW[2], *eb[2], *hW[2], *hb[2], *g0[2], *b0[2];
  const float *efW[2], *efb[2], *convb[2], *outW[2], *outb[2], *lng[2], *lnb[2];
  float *h, *prev0, *agg, *eh, *T;
  int *deg;
  float *out;
};

__device__ __forceinline__ float lrelu(float v){ return v > 0.f ? v : 0.01f * v; }

__device__ __forceinline__ float wsum(float v){
  #pragma unroll
  for (int off = 32; off > 0; off >>= 1) v += __shfl_xor(v, off, 64);
  return v;
}

// ---- A: edge embedding (both sides) + degree counts -------------------------
__global__ __launch_bounds__(256) void k_edge(Params p){
  __shared__ float sW[2][256], sb[2][16];
  int t = threadIdx.x;
  sW[0][t] = p.eW[0][t];
  sW[1][t] = p.eW[1][t];
  if (t < 16){ sb[0][t] = p.eb[0][t]; sb[1][t] = p.eb[1][t]; }
  __syncthreads();

  int e = blockIdx.x * 256 + t;
  int side = e >= ELIG;
  int el = side ? e - ELIG : e;
  const float* ex = (side ? p.rec_e : p.lig_e) + (size_t)el * 16;

  float x[16];
  #pragma unroll
  for (int j = 0; j < 16; j += 4){
    float4 v = *(const float4*)(ex + j);
    x[j] = v.x; x[j+1] = v.y; x[j+2] = v.z; x[j+3] = v.w;
  }
  float s[16];
  #pragma unroll
  for (int k = 0; k < 16; k++){
    float acc = sb[side][k];
    #pragma unroll
    for (int j = 0; j < 16; j++) acc += x[j] * sW[side][j*16 + k];
    s[k] = acc;
  }
  float* ehp = p.eh + (size_t)e * 16;
  #pragma unroll
  for (int k = 0; k < 16; k += 4)
    *(float4*)(ehp + k) = make_float4(s[k], s[k+1], s[k+2], s[k+3]);

  int dst = side ? NLIG + p.rec_dst[el] : p.lig_dst[el];
  atomicAdd(&p.deg[dst], 1);
}

// ---- B: node embedding + LN0 (one 64-thread block per node) -----------------
__global__ __launch_bounds__(64) void k_node(Params p){
  int n = blockIdx.x;
  int side = n >= NLIG;
  int nl = side ? n - NLIG : n;
  int nin = side ? 40 : 32;
  const float* x = (side ? p.rec_x : p.lig_x) + (size_t)nl * nin;

  __shared__ float sx[40], st[64];
  int f = threadIdx.x;
  if (f < nin) sx[f] = x[f];
  __syncthreads();

  float tv = p.nb[side][f];
  const float* nw = p.nW[side];
  for (int j = 0; j < nin; j++) tv += sx[j] * nw[j*64 + f];
  st[f] = lrelu(tv);
  __syncthreads();

  float hv = p.hb[side][f];
  const float* hw = p.hW[side];
  #pragma unroll 8
  for (int j = 0; j < 64; j++) hv += st[j] * hw[j*64 + f];

  float m = wsum(hv) * (1.f/64.f);
  float d = hv - m;
  float v = wsum(d*d) * (1.f/64.f);
  p.h[(size_t)n*64 + f] = d * rsqrtf(v + 1e-5f) * p.g0[side][f] + p.b0[side][f];
}

// ---- C1: T[n, ks*64+o] = sum_j lrelu(h[n,j]) * W[ks][j][o]  -----------------
// grid (80 row-tiles, 17 slots), block 256; 64x64 tile, 4x4 micro-tile.
__global__ __launch_bounds__(256) void k_tmat(Params p, int layer){
  int bt = blockIdx.x;             // 0..79 : 16 lig tiles then 64 rec tiles
  int ks = blockIdx.y;             // 0..16
  int side = bt >= 16;
  int row0 = side ? NLIG + (bt-16)*64 : bt*64;
  const float* Wp = (ks < 16) ? (p.efW[side] + (size_t)layer*16*4096 + (size_t)ks*4096)
                              : (p.efb[side] + (size_t)layer*4096);

  __shared__ float sh[64][65];
  __shared__ float sw[64][64];
  int t = threadIdx.x;
  for (int idx = t; idx < 4096; idx += 256){
    int r = idx >> 6, c = idx & 63;
    sh[r][c] = lrelu(p.h[(size_t)(row0 + r)*64 + c]);
    sw[r][c] = Wp[idx];
  }
  __syncthreads();

  int tm = t >> 4, tn = t & 15;
  float acc[4][4] = {};
  #pragma unroll 4
  for (int j = 0; j < 64; j++){
    float4 wv = *(const float4*)&sw[j][tn*4];
    float a0 = sh[tm*4+0][j], a1 = sh[tm*4+1][j], a2 = sh[tm*4+2][j], a3 = sh[tm*4+3][j];
    acc[0][0] += a0*wv.x; acc[0][1] += a0*wv.y; acc[0][2] += a0*wv.z; acc[0][3] += a0*wv.w;
    acc[1][0] += a1*wv.x; acc[1][1] += a1*wv.y; acc[1][2] += a1*wv.z; acc[1][3] += a1*wv.w;
    acc[2][0] += a2*wv.x; acc[2][1] += a2*wv.y; acc[2][2] += a2*wv.z; acc[2][3] += a2*wv.w;
    acc[3][0] += a3*wv.x; acc[3][1] += a3*wv.y; acc[3][2] += a3*wv.z; acc[3][3] += a3*wv.w;
  }
  #pragma unroll
  for (int i = 0; i < 4; i++){
    float* Tp = p.T + (size_t)(row0 + tm*4 + i)*TSTRIDE + ks*64 + tn*4;
    *(float4*)Tp = make_float4(acc[i][0], acc[i][1], acc[i][2], acc[i][3]);
  }
}

// ---- C2: per-edge message + atomic aggregation ------------------------------
__global__ __launch_bounds__(256) void k_msg(Params p){
  int t = threadIdx.x;
  int eg = blockIdx.x*4 + (t >> 6);
  int o = t & 63;
  int side = eg >= ELIG;
  int el = side ? eg - ELIG : eg;
  int src = side ? NLIG + p.rec_src[el] : p.lig_src[el];
  int dst = side ? NLIG + p.rec_dst[el] : p.lig_dst[el];

  const float* Trow = p.T + (size_t)src * TSTRIDE;
  const float* ehp = p.eh + (size_t)eg * 16;
  float e[16];
  #pragma unroll
  for (int k = 0; k < 16; k += 4){
    float4 v = *(const float4*)(ehp + k);
    e[k] = v.x; e[k+1] = v.y; e[k+2] = v.z; e[k+3] = v.w;
  }
  float m = Trow[16*64 + o];              // bias slot
  #pragma unroll
  for (int k = 0; k < 16; k++) m += e[k] * Trow[k*64 + o];
  atomicAdd(&p.agg[(size_t)dst*64 + o], m);
}

// ---- C3: node update: /deg + convb, lrelu, @outW, LN, residual --------------
__global__ __launch_bounds__(64) void k_upd(Params p, int layer){
  int n = blockIdx.x;
  int side = n >= NLIG;
  int f = threadIdx.x;

  float a = p.agg[(size_t)n*64 + f];
  p.agg[(size_t)n*64 + f] = 0.f;         // ready for next layer
  float dg = fmaxf((float)p.deg[n], 1.f);
  a = lrelu(a / dg + p.convb[side][layer*64 + f]);

  __shared__ float sa[64];
  sa[f] = a;
  __syncthreads();

  float hv = p.outb[side][layer*64 + f];
  const float* ow = p.outW[side] + (size_t)layer*4096;
  #pragma unroll 8
  for (int j = 0; j < 64; j++) hv += sa[j] * ow[j*64 + f];

  float m = wsum(hv) * (1.f/64.f);
  float d = hv - m;
  float v = wsum(d*d) * (1.f/64.f);
  float o = d * rsqrtf(v + 1e-5f) * p.lng[side][layer*64 + f] + p.lnb[side][layer*64 + f];
  if (layer == 2) o += p.prev0[(size_t)n*64 + f];
  p.h[(size_t)n*64 + f] = o;
  if (layer == 0) p.prev0[(size_t)n*64 + f] = o;
}

// ---- D: scoring op[b,l,r] = <lig_h[b,l], rec_h[b,r]>, out[b] = mean ---------
__global__ __launch_bounds__(256) void k_score(Params p){
  int b = blockIdx.x, rt = blockIdx.y;   // 16 x 4
  __shared__ float sl[64][65], sr[64][65];
  int t = threadIdx.x;
  for (int idx = t; idx < 4096; idx += 256){
    int r = idx >> 6, c = idx & 63;
    sl[r][c] = p.h[(size_t)(b*64 + r)*64 + c];
    sr[r][c] = p.h[(size_t)(NLIG + b*256 + rt*64 + r)*64 + c];
  }
  __syncthreads();

  int tl = t >> 4, tr = t & 15;
  float acc[4][4] = {};
  #pragma unroll 4
  for (int f2 = 0; f2 < 64; f2++){
    float a0 = sl[tl*4+0][f2], a1 = sl[tl*4+1][f2], a2 = sl[tl*4+2][f2], a3 = sl[tl*4+3][f2];
    float b0 = sr[tr*4+0][f2], b1 = sr[tr*4+1][f2], b2 = sr[tr*4+2][f2], b3 = sr[tr*4+3][f2];
    acc[0][0] += a0*b0; acc[0][1] += a0*b1; acc[0][2] += a0*b2; acc[0][3] += a0*b3;
    acc[1][0] += a1*b0; acc[1][1] += a1*b1; acc[1][2] += a1*b2; acc[1][3] += a1*b3;
    acc[2][0] += a2*b0; acc[2][1] += a2*b1; acc[2][2] += a2*b2; acc[2][3] += a2*b3;
    acc[3][0] += a3*b0; acc[3][1] += a3*b1; acc[3][2] += a3*b2; acc[3][3] += a3*b3;
  }
  float psum = 0.f;
  #pragma unroll
  for (int i = 0; i < 4; i++){
    float4 v = make_float4(acc[i][0], acc[i][1], acc[i][2], acc[i][3]);
    *(float4*)&p.out[16 + (size_t)b*16384 + (size_t)(tl*4+i)*256 + rt*64 + tr*4] = v;
    psum += v.x + v.y + v.z + v.w;
  }
  psum = wsum(psum);
  __shared__ float ps[4];
  if ((t & 63) == 0) ps[t >> 6] = psum;
  __syncthreads();
  if (t == 0)
    atomicAdd(&p.out[b], (ps[0]+ps[1]+ps[2]+ps[3]) * (1.f/16384.f));
}

extern "C" void kernel_launch(void* const* d_in, const int* in_sizes, int n_in,
                              void* d_out, int out_size, void* d_ws, size_t ws_size,
                              hipStream_t stream){
  Params p;
  p.lig_x  = (const float*)d_in[0];
  p.rec_x  = (const float*)d_in[1];
  p.lig_e  = (const float*)d_in[2];
  p.rec_e  = (const float*)d_in[3];
  p.lig_src = (const int*)d_in[4];
  p.lig_dst = (const int*)d_in[5];
  p.rec_src = (const int*)d_in[6];
  p.rec_dst = (const int*)d_in[7];
  for (int s = 0; s < 2; s++){
    const int o = 8 + s*15;
    p.nW[s]   = (const float*)d_in[o+0];  p.nb[s]   = (const float*)d_in[o+1];
    p.eW[s]   = (const float*)d_in[o+2];  p.eb[s]   = (const float*)d_in[o+3];
    p.hW[s]   = (const float*)d_in[o+4];  p.hb[s]   = (const float*)d_in[o+5];
    p.g0[s]   = (const float*)d_in[o+6];  p.b0[s]   = (const float*)d_in[o+7];
    p.efW[s]  = (const float*)d_in[o+8];  p.efb[s]  = (const float*)d_in[o+9];
    p.convb[s]= (const float*)d_in[o+10]; p.outW[s] = (const float*)d_in[o+11];
    p.outb[s] = (const float*)d_in[o+12]; p.lng[s]  = (const float*)d_in[o+13];
    p.lnb[s]  = (const float*)d_in[o+14];
  }
  float* W = (float*)d_ws;
  p.h     = W; W += (size_t)NTOT*64;
  p.prev0 = W; W += (size_t)NTOT*64;
  p.agg   = W; W += (size_t)NTOT*64;
  p.eh    = W; W += (size_t)ETOT*16;
  p.T     = W; W += (size_t)NTOT*TSTRIDE;
  p.deg   = (int*)W;
  p.out   = (float*)d_out;

  hipMemsetAsync(p.deg, 0, NTOT*sizeof(int), stream);
  hipMemsetAsync(p.agg, 0, (size_t)NTOT*64*sizeof(float), stream);
  hipMemsetAsync(d_out, 0, 16*sizeof(float), stream);

  k_edge<<<ETOT/256, 256, 0, stream>>>(p);
  k_node<<<NTOT, 64, 0, stream>>>(p);
  for (int layer = 0; layer < 3; layer++){
    k_tmat<<<dim3(80, 17), 256, 0, stream>>>(p, layer);
    k_msg<<<ETOT/4, 256, 0, stream>>>(p);
    k_upd<<<NTOT, 64, 0, stream>>>(p, layer);
  }
  k_score<<<dim3(16, 4), 256, 0, stream>>>(p);
}

// Round 2
// 135.496 us; speedup vs baseline: 1.1976x; 1.1976x over previous
//
#include <hip/hip_runtime.h>
#include <hip/hip_bf16.h>

#define NLIG 1024
#define NREC 4096
#define NTOT 5120
#define ELIG 8192
#define ETOT 40960
#define TCOLS 1088   // 17 slots * 64 (slot 16 = efb bias slot)

typedef __bf16 bf16x8 __attribute__((ext_vector_type(8)));
typedef float f32x4 __attribute__((ext_vector_type(4)));

struct Params {
  const float *lig_x, *rec_x, *lig_e, *rec_e;
  const int *lig_src, *lig_dst, *rec_src, *rec_dst;
  const float *nW[2], *nb[2], *eW[2], *eb[2], *hW[2], *hb[2], *g0[2], *b0[2];
  const float *efW[2], *efb[2], *convb[2], *outW[2], *outb[2], *lng[2], *lnb[2];
  float *h, *prev0, *agg, *eh;
  __bf16 *T, *Abf, *Wp;
  int *deg;
  float *out;
};

__device__ __forceinline__ float lrelu(float v){ return v > 0.f ? v : 0.01f * v; }

__device__ __forceinline__ float wsum(float v){
  #pragma unroll
  for (int off = 32; off > 0; off >>= 1) v += __shfl_xor(v, off, 64);
  return v;
}

// ---- P: pack W_all = [efW slots 0..15 | efb] into MFMA B-fragment order ------
// Wp[sl][ct][kk][lane][j] = W_all[i = kk*32 + (lane>>4)*8 + j][o = ct*16 + (lane&15)]
// Any misassumption of the hardware k-mapping cancels because A-frags use the
// same (lane>>4)*8+j convention (MFMA is invariant under a shared k-permutation).
__global__ __launch_bounds__(256) void k_prepW(Params p){
  int id = blockIdx.x * 256 + threadIdx.x;      // 52224 total
  int l  = id & 63;
  int t2 = id >> 6;
  int kk = t2 & 1;
  int t3 = t2 >> 1;
  int ct = t3 % 68;
  int sl = t3 / 68;            // side*3 + layer
  int side = sl / 3, layer = sl % 3;
  int ocol = ct*16 + (l & 15);
  int kslot = ocol >> 6, oo = ocol & 63;
  const float* src = (kslot < 16)
      ? (p.efW[side] + (size_t)layer*16*4096 + (size_t)kslot*4096)
      : (p.efb[side] + (size_t)layer*4096);
  bf16x8 w;
  #pragma unroll
  for (int j = 0; j < 8; j++){
    int i = kk*32 + (l >> 4)*8 + j;
    w[j] = (__bf16)src[i*64 + oo];
  }
  ((bf16x8*)p.Wp)[(size_t)sl*68*2*64 + (ct*2 + kk)*64 + l] = w;
}

// ---- A: edge embedding (both sides) + degree counts -------------------------
__global__ __launch_bounds__(256) void k_edge(Params p){
  __shared__ float sW[2][256], sb[2][16];
  int t = threadIdx.x;
  sW[0][t] = p.eW[0][t];
  sW[1][t] = p.eW[1][t];
  if (t < 16){ sb[0][t] = p.eb[0][t]; sb[1][t] = p.eb[1][t]; }
  __syncthreads();

  int e = blockIdx.x * 256 + t;
  int side = e >= ELIG;
  int el = side ? e - ELIG : e;
  const float* ex = (side ? p.rec_e : p.lig_e) + (size_t)el * 16;

  float x[16];
  #pragma unroll
  for (int j = 0; j < 16; j += 4){
    float4 v = *(const float4*)(ex + j);
    x[j] = v.x; x[j+1] = v.y; x[j+2] = v.z; x[j+3] = v.w;
  }
  float s[16];
  #pragma unroll
  for (int k = 0; k < 16; k++){
    float acc = sb[side][k];
    #pragma unroll
    for (int j = 0; j < 16; j++) acc += x[j] * sW[side][j*16 + k];
    s[k] = acc;
  }
  float* ehp = p.eh + (size_t)e * 16;
  #pragma unroll
  for (int k = 0; k < 16; k += 4)
    *(float4*)(ehp + k) = make_float4(s[k], s[k+1], s[k+2], s[k+3]);

  int dst = side ? NLIG + p.rec_dst[el] : p.lig_dst[el];
  atomicAdd(&p.deg[dst], 1);
}

// ---- B: node embedding + LN0; also emit Abf = bf16(lrelu(h)) ----------------
__global__ __launch_bounds__(64) void k_node(Params p){
  int n = blockIdx.x;
  int side = n >= NLIG;
  int nl = side ? n - NLIG : n;
  int nin = side ? 40 : 32;
  const float* x = (side ? p.rec_x : p.lig_x) + (size_t)nl * nin;

  __shared__ float sx[40], st[64];
  int f = threadIdx.x;
  if (f < nin) sx[f] = x[f];
  __syncthreads();

  float tv = p.nb[side][f];
  const float* nw = p.nW[side];
  for (int j = 0; j < nin; j++) tv += sx[j] * nw[j*64 + f];
  st[f] = lrelu(tv);
  __syncthreads();

  float hv = p.hb[side][f];
  const float* hw = p.hW[side];
  #pragma unroll 8
  for (int j = 0; j < 64; j++) hv += st[j] * hw[j*64 + f];

  float m = wsum(hv) * (1.f/64.f);
  float d = hv - m;
  float v = wsum(d*d) * (1.f/64.f);
  float o = d * rsqrtf(v + 1e-5f) * p.g0[side][f] + p.b0[side][f];
  p.h[(size_t)n*64 + f] = o;
  p.Abf[(size_t)n*64 + f] = (__bf16)lrelu(o);
}

// ---- C1 (MFMA): T[n, ks*64+o] = sum_i Abf[n,i] * W_all[i, ...] --------------
// grid (80 row-tiles, 17 col-slots), 4 waves/block, wave = 16 rows x 64 cols.
__global__ __launch_bounds__(256) void k_tmat(Params p, int layer){
  int bt = blockIdx.x, ks = blockIdx.y;
  int side = bt >= 16;
  int row0 = side ? NLIG + (bt-16)*64 : bt*64;
  int wid = threadIdx.x >> 6, lane = threadIdx.x & 63;
  int r0 = row0 + wid*16;

  const bf16x8* A = (const bf16x8*)(p.Abf + (size_t)(r0 + (lane & 15))*64 + (lane >> 4)*8);
  bf16x8 a0 = A[0];       // k 0..31 slice (this lane's 8)
  bf16x8 a1 = A[4];       // k 32..63 slice (+32 elems)

  const bf16x8* Wb = (const bf16x8*)p.Wp + (size_t)(side*3 + layer)*68*2*64;
  int orow = (lane >> 4)*4;

  #pragma unroll
  for (int c = 0; c < 4; c++){
    int ct = ks*4 + c;
    bf16x8 b0 = Wb[(ct*2 + 0)*64 + lane];
    bf16x8 b1 = Wb[(ct*2 + 1)*64 + lane];
    f32x4 d = {0.f, 0.f, 0.f, 0.f};
    d = __builtin_amdgcn_mfma_f32_16x16x32_bf16(a0, b0, d, 0, 0, 0);
    d = __builtin_amdgcn_mfma_f32_16x16x32_bf16(a1, b1, d, 0, 0, 0);
    int col = ct*16 + (lane & 15);
    __bf16* Tp = p.T + (size_t)(r0 + orow)*TCOLS + col;
    Tp[0*TCOLS] = (__bf16)d[0];
    Tp[1*TCOLS] = (__bf16)d[1];
    Tp[2*TCOLS] = (__bf16)d[2];
    Tp[3*TCOLS] = (__bf16)d[3];
  }
}

// ---- C2: per-edge message + atomic aggregation (T in bf16) ------------------
__global__ __launch_bounds__(256) void k_msg(Params p){
  int t = threadIdx.x;
  int eg = blockIdx.x*4 + (t >> 6);
  int o = t & 63;
  int side = eg >= ELIG;
  int el = side ? eg - ELIG : eg;
  int src = side ? NLIG + p.rec_src[el] : p.lig_src[el];
  int dst = side ? NLIG + p.rec_dst[el] : p.lig_dst[el];

  const __bf16* Trow = p.T + (size_t)src * TCOLS;
  const float* ehp = p.eh + (size_t)eg * 16;
  float e[16];
  #pragma unroll
  for (int k = 0; k < 16; k += 4){
    float4 v = *(const float4*)(ehp + k);
    e[k] = v.x; e[k+1] = v.y; e[k+2] = v.z; e[k+3] = v.w;
  }
  float m = (float)Trow[16*64 + o];       // bias slot
  #pragma unroll
  for (int k = 0; k < 16; k++) m += e[k] * (float)Trow[k*64 + o];
  atomicAdd(&p.agg[(size_t)dst*64 + o], m);
}

// ---- C3: node update; also emit Abf for the next layer ----------------------
__global__ __launch_bounds__(64) void k_upd(Params p, int layer){
  int n = blockIdx.x;
  int side = n >= NLIG;
  int f = threadIdx.x;

  float a = p.agg[(size_t)n*64 + f];
  p.agg[(size_t)n*64 + f] = 0.f;         // ready for next layer
  float dg = fmaxf((float)p.deg[n], 1.f);
  a = lrelu(a / dg + p.convb[side][layer*64 + f]);

  __shared__ float sa[64];
  sa[f] = a;
  __syncthreads();

  float hv = p.outb[side][layer*64 + f];
  const float* ow = p.outW[side] + (size_t)layer*4096;
  #pragma unroll 8
  for (int j = 0; j < 64; j++) hv += sa[j] * ow[j*64 + f];

  float m = wsum(hv) * (1.f/64.f);
  float d = hv - m;
  float v = wsum(d*d) * (1.f/64.f);
  float o = d * rsqrtf(v + 1e-5f) * p.lng[side][layer*64 + f] + p.lnb[side][layer*64 + f];
  if (layer == 2) o += p.prev0[(size_t)n*64 + f];
  p.h[(size_t)n*64 + f] = o;
  if (layer == 0) p.prev0[(size_t)n*64 + f] = o;
  p.Abf[(size_t)n*64 + f] = (__bf16)lrelu(o);
}

// ---- D: scoring op[b,l,r] = <lig_h[b,l], rec_h[b,r]>, out[b] = mean ---------
__global__ __launch_bounds__(256) void k_score(Params p){
  int b = blockIdx.x, rt = blockIdx.y;   // 16 x 4
  __shared__ float sl[64][65], sr[64][65];
  int t = threadIdx.x;
  for (int idx = t; idx < 4096; idx += 256){
    int r = idx >> 6, c = idx & 63;
    sl[r][c] = p.h[(size_t)(b*64 + r)*64 + c];
    sr[r][c] = p.h[(size_t)(NLIG + b*256 + rt*64 + r)*64 + c];
  }
  __syncthreads();

  int tl = t >> 4, tr = t & 15;
  float acc[4][4] = {};
  #pragma unroll 4
  for (int f2 = 0; f2 < 64; f2++){
    float a0 = sl[tl*4+0][f2], a1 = sl[tl*4+1][f2], a2 = sl[tl*4+2][f2], a3 = sl[tl*4+3][f2];
    float b0 = sr[tr*4+0][f2], b1 = sr[tr*4+1][f2], b2 = sr[tr*4+2][f2], b3 = sr[tr*4+3][f2];
    acc[0][0] += a0*b0; acc[0][1] += a0*b1; acc[0][2] += a0*b2; acc[0][3] += a0*b3;
    acc[1][0] += a1*b0; acc[1][1] += a1*b1; acc[1][2] += a1*b2; acc[1][3] += a1*b3;
    acc[2][0] += a2*b0; acc[2][1] += a2*b1; acc[2][2] += a2*b2; acc[2][3] += a2*b3;
    acc[3][0] += a3*b0; acc[3][1] += a3*b1; acc[3][2] += a3*b2; acc[3][3] += a3*b3;
  }
  float psum = 0.f;
  #pragma unroll
  for (int i = 0; i < 4; i++){
    float4 v = make_float4(acc[i][0], acc[i][1], acc[i][2], acc[i][3]);
    *(float4*)&p.out[16 + (size_t)b*16384 + (size_t)(tl*4+i)*256 + rt*64 + tr*4] = v;
    psum += v.x + v.y + v.z + v.w;
  }
  psum = wsum(psum);
  __shared__ float ps[4];
  if ((t & 63) == 0) ps[t >> 6] = psum;
  __syncthreads();
  if (t == 0)
    atomicAdd(&p.out[b], (ps[0]+ps[1]+ps[2]+ps[3]) * (1.f/16384.f));
}

extern "C" void kernel_launch(void* const* d_in, const int* in_sizes, int n_in,
                              void* d_out, int out_size, void* d_ws, size_t ws_size,
                              hipStream_t stream){
  Params p;
  p.lig_x  = (const float*)d_in[0];
  p.rec_x  = (const float*)d_in[1];
  p.lig_e  = (const float*)d_in[2];
  p.rec_e  = (const float*)d_in[3];
  p.lig_src = (const int*)d_in[4];
  p.lig_dst = (const int*)d_in[5];
  p.rec_src = (const int*)d_in[6];
  p.rec_dst = (const int*)d_in[7];
  for (int s = 0; s < 2; s++){
    const int o = 8 + s*15;
    p.nW[s]   = (const float*)d_in[o+0];  p.nb[s]   = (const float*)d_in[o+1];
    p.eW[s]   = (const float*)d_in[o+2];  p.eb[s]   = (const float*)d_in[o+3];
    p.hW[s]   = (const float*)d_in[o+4];  p.hb[s]   = (const float*)d_in[o+5];
    p.g0[s]   = (const float*)d_in[o+6];  p.b0[s]   = (const float*)d_in[o+7];
    p.efW[s]  = (const float*)d_in[o+8];  p.efb[s]  = (const float*)d_in[o+9];
    p.convb[s]= (const float*)d_in[o+10]; p.outW[s] = (const float*)d_in[o+11];
    p.outb[s] = (const float*)d_in[o+12]; p.lng[s]  = (const float*)d_in[o+13];
    p.lnb[s]  = (const float*)d_in[o+14];
  }
  char* W = (char*)d_ws;
  p.h     = (float*)W;  W += (size_t)NTOT*64*4;
  p.prev0 = (float*)W;  W += (size_t)NTOT*64*4;
  p.agg   = (float*)W;  W += (size_t)NTOT*64*4;
  p.eh    = (float*)W;  W += (size_t)ETOT*16*4;
  p.T     = (__bf16*)W; W += (size_t)NTOT*TCOLS*2;
  p.Abf   = (__bf16*)W; W += (size_t)NTOT*64*2;
  p.Wp    = (__bf16*)W; W += (size_t)2*3*68*2*64*8*2;
  p.deg   = (int*)W;
  p.out   = (float*)d_out;

  hipMemsetAsync(p.deg, 0, NTOT*sizeof(int), stream);
  hipMemsetAsync(p.agg, 0, (size_t)NTOT*64*sizeof(float), stream);
  hipMemsetAsync(d_out, 0, 16*sizeof(float), stream);

  k_prepW<<<204, 256, 0, stream>>>(p);
  k_edge<<<ETOT/256, 256, 0, stream>>>(p);
  k_node<<<NTOT, 64, 0, stream>>>(p);
  for (int layer = 0; layer < 3; layer++){
    k_tmat<<<dim3(80, 17), 256, 0, stream>>>(p, layer);
    k_msg<<<ETOT/4, 256, 0, stream>>>(p);
    k_upd<<<NTOT, 64, 0, stream>>>(p, layer);
  }
  k_score<<<dim3(16, 4), 256, 0, stream>>>(p);
}